// Round 5
// baseline (28.573 us; speedup 1.0000x reference)
//
#include <hip/hip_runtime.h>

// TrajLoss: pos = cumsum(pred.reshape(B,T,2), axis=1);
// loss = sum((pos_x - true[:, :T])^2 + (pos_y - true[:, T:])^2)
// B=8192, L=2048, T=1024. traj_du_true (d_in[1]) is unused by the reference.
//
// R4 post-mortem: atomic floor confirmed (43->27 us). Remaining limiter:
// L1/TA line-request amplification. R4's lane-stride-64B loads issue ~768
// line-requests/wave for 256 unique lines (3x). This version is fully
// coalesced (1x): pred float4 at j*64+lane (1 KiB contiguous per instr),
// truth float2 at j*64+lane. Cumsum = 8 wave scans (one per j-chunk,
// interleaved for ILP) + serial cross-j carry. Per-block partial -> d_ws
// plain store; 1-block K2 reduces 2048 partials (zero contended atomics).

constexpr int L_DIM = 2048;
constexpr int T_DIM = 1024;          // L/2
constexpr int ROWS_PER_BLOCK = 4;    // 4 waves x 64 lanes = 256 threads
constexpr int NJ = 8;                // float4 chunks per lane: 8*64*4 = 2048 floats

__global__ __launch_bounds__(256, 4) void traj_loss_kernel(
    const float* __restrict__ pred,
    const float* __restrict__ pos_true,
    float* __restrict__ partials,
    int B)
{
    const int wid  = threadIdx.x >> 6;
    const int lane = threadIdx.x & 63;
    const int row  = blockIdx.x * ROWS_PER_BLOCK + wid;

    float acc = 0.0f;

    if (row < B) {
        const float4* p4  = reinterpret_cast<const float4*>(pred + (size_t)row * L_DIM);          // 512 float4
        const float2* tX2 = reinterpret_cast<const float2*>(pos_true + (size_t)row * L_DIM);      // 512 float2
        const float2* tY2 = reinterpret_cast<const float2*>(pos_true + (size_t)row * L_DIM + T_DIM);

        // ---- fully-coalesced loads, ALL issued up front (24 instrs/lane) ----
        // float4 k = j*64+lane holds (dx,dy) for t=2k and t=2k+1;
        // float2 k of tx/ty holds truth for the same two t.
        float4 v[NJ];
        float2 tx[NJ], ty[NJ];
#pragma unroll
        for (int j = 0; j < NJ; ++j) v[j]  = p4[j * 64 + lane];
#pragma unroll
        for (int j = 0; j < NJ; ++j) tx[j] = tX2[j * 64 + lane];
#pragma unroll
        for (int j = 0; j < NJ; ++j) ty[j] = tY2[j * 64 + lane];

        // pin load issue before compute (waitcnt still lands at first use)
        asm volatile("" ::: "memory");

        // ---- per-chunk pair sums; 8 independent wave inclusive scans ----
        float ox[NJ], oy[NJ];   // own pair sums
        float ix[NJ], iy[NJ];   // inclusive lane-scan of pair sums
#pragma unroll
        for (int j = 0; j < NJ; ++j) {
            ox[j] = v[j].x + v[j].z;
            oy[j] = v[j].y + v[j].w;
            ix[j] = ox[j];
            iy[j] = oy[j];
        }
#pragma unroll
        for (int d = 1; d < 64; d <<= 1) {
#pragma unroll
            for (int j = 0; j < NJ; ++j) {
                float ux = __shfl_up(ix[j], d);
                float uy = __shfl_up(iy[j], d);
                if (lane >= d) { ix[j] += ux; iy[j] += uy; }
            }
        }

        // ---- serial carry across j + squared error ----
        float cx = 0.0f, cy = 0.0f;
#pragma unroll
        for (int j = 0; j < NJ; ++j) {
            const float totx = __shfl(ix[j], 63);   // wave total of chunk j
            const float toty = __shfl(iy[j], 63);
            const float bx = cx + (ix[j] - ox[j]);  // exclusive prefix for this lane
            const float by = cy + (iy[j] - oy[j]);

            const float px0 = bx  + v[j].x;         // pos_x at t=2k
            const float px1 = px0 + v[j].z;         // pos_x at t=2k+1
            const float py0 = by  + v[j].y;
            const float py1 = py0 + v[j].w;

            float e;
            e = px0 - tx[j].x; acc += e * e;
            e = px1 - tx[j].y; acc += e * e;
            e = py0 - ty[j].x; acc += e * e;
            e = py1 - ty[j].y; acc += e * e;

            cx += totx;
            cy += toty;
        }
    }

    // ---- wave reduce ----
#pragma unroll
    for (int d = 32; d >= 1; d >>= 1) acc += __shfl_xor(acc, d);

    __shared__ float warp_sums[ROWS_PER_BLOCK];
    if (lane == 0) warp_sums[wid] = acc;
    __syncthreads();

    if (threadIdx.x == 0) {
        float s = 0.0f;
#pragma unroll
        for (int w = 0; w < ROWS_PER_BLOCK; ++w) s += warp_sums[w];
        partials[blockIdx.x] = s;   // plain store — no atomic contention
    }
}

__global__ __launch_bounds__(256) void reduce_kernel(
    const float* __restrict__ partials, float* __restrict__ out, int n)
{
    const int lane = threadIdx.x & 63;
    const int wid  = threadIdx.x >> 6;

    float s = 0.0f;
    for (int i = threadIdx.x; i < n; i += 256) s += partials[i];

#pragma unroll
    for (int d = 32; d >= 1; d >>= 1) s += __shfl_xor(s, d);

    __shared__ float ws[4];
    if (lane == 0) ws[wid] = s;
    __syncthreads();

    if (threadIdx.x == 0) out[0] = ws[0] + ws[1] + ws[2] + ws[3];
}

extern "C" void kernel_launch(void* const* d_in, const int* in_sizes, int n_in,
                              void* d_out, int out_size, void* d_ws, size_t ws_size,
                              hipStream_t stream) {
    const float* pred     = (const float*)d_in[0];  // traj_pred
    // d_in[1] = traj_du_true — unused by the reference
    const float* pos_true = (const float*)d_in[2];  // traj_pos_true
    float* out      = (float*)d_out;
    float* partials = (float*)d_ws;                 // grid floats, overwritten every call

    const int B = in_sizes[0] / L_DIM;
    const int grid = (B + ROWS_PER_BLOCK - 1) / ROWS_PER_BLOCK;   // 2048

    traj_loss_kernel<<<grid, 256, 0, stream>>>(pred, pos_true, partials, B);
    reduce_kernel<<<1, 256, 0, stream>>>(partials, out, grid);
}